// Round 13
// baseline (355.450 us; speedup 1.0000x reference)
//
#include <hip/hip_runtime.h>
#include <stdint.h>
#include <stddef.h>

// Problem constants (DINOv2 self-attention)
#define SQ     1370              // sequence length
#define SP     1408              // padded V^T row stride (covers 22 j-tiles of 64)
#define NJ     22                // ceil(SQ/64) key tiles (even -> 11 pairs)
#define NBATCH 8
#define NHEADS 16
#define DH     64                // head dim
#define DM     1024              // model dim
#define MROWS  (NBATCH * SQ)     // 10960 flattened rows
#define MT     86                // m-tiles (128 rows each)
#define NQT    6                 // ceil(SQ/256) q-tiles for attn

typedef _Float16 f16;
typedef __attribute__((ext_vector_type(8))) _Float16 f16x8;
typedef __attribute__((ext_vector_type(4))) _Float16 f16x4;
typedef __attribute__((ext_vector_type(2))) _Float16 f16x2;
typedef __attribute__((ext_vector_type(4))) float    f32x4;

#define MFMA_16x16x32_F16(a, b, c) __builtin_amdgcn_mfma_f32_16x16x32_f16((a), (b), (c), 0, 0, 0)
#define MFMA_16x16x16_F16(a, b, c) __builtin_amdgcn_mfma_f32_16x16x16f16((a), (b), (c), 0, 0, 0)

// Async global->LDS DMA, 16 B per lane. LDS dest must be wave-uniform base +
// lane*16 (hardware constraint); the global side is an ordinary per-lane addr.
__device__ __forceinline__ void load_lds_16(const f16* g, f16* l) {
    __builtin_amdgcn_global_load_lds(
        (const __attribute__((address_space(1))) void*)g,
        (__attribute__((address_space(3))) void*)l, 16, 0, 0);
}

// ---------------------------------------------------------------------------
// Kernel 0: fp32 -> f16 convert (hs + the three weight matrices).
// ---------------------------------------------------------------------------
__global__ __launch_bounds__(256) void cvt_kernel(
    const float* __restrict__ s0, const float* __restrict__ s1,
    const float* __restrict__ s2, const float* __restrict__ s3,
    f16* __restrict__ d0, f16* __restrict__ d1,
    f16* __restrict__ d2, f16* __restrict__ d3,
    int n0, int n1, int n2, int n3)     // counts in float4 units
{
    const float* s; f16* d; int n;
    switch (blockIdx.y) {
        case 0:  s = s0; d = d0; n = n0; break;
        case 1:  s = s1; d = d1; n = n1; break;
        case 2:  s = s2; d = d2; n = n2; break;
        default: s = s3; d = d3; n = n3; break;
    }
    const int stride = gridDim.x * blockDim.x;
    for (int i = blockIdx.x * blockDim.x + threadIdx.x; i < n; i += stride) {
        const float4 v = ((const float4*)s)[i];
        ((f16x4*)d)[i] = (f16x4){(f16)v.x, (f16)v.y, (f16)v.z, (f16)v.w};
    }
}

// ---------------------------------------------------------------------------
// Kernel 1: QKV projection GEMM — R4 VERBATIM (best measured: ~143 µs).
// f16 inputs, BK=64, tile 128x128, double-buffered: per K-step, issue the
// next step's 8 global_load_lds right after the barrier, then compute the
// current step from the other buffer. LDS 64 KB -> 2 blocks/CU.
// ---------------------------------------------------------------------------
__global__ __launch_bounds__(256) void qkv_gemm_kernel(
    const f16* __restrict__ A,        // [MROWS][DM] f16
    const f16* __restrict__ Wq16, const f16* __restrict__ Wk16,
    const f16* __restrict__ Wv16,
    const float* __restrict__ bq, const float* __restrict__ bk,
    const float* __restrict__ bv,
    f16* __restrict__ Qo, f16* __restrict__ Ko, f16* __restrict__ Vto)
{
    __shared__ f16 As[2][128 * 64];   // 32 KB
    __shared__ f16 Bs[2][128 * 64];   // 32 KB

    // --- XCD-aware work decomposition ---
    const int L = blockIdx.x;         // 0..2063
    const int x = L & 7;              // XCD (round-robin dispatch assumption)
    const int g = L >> 3;             // per-XCD sequence 0..257
    const int z = g / MT;             // 0..2  (z outer)
    const int w = x * MT + (g % MT);  // within-z work id 0..687, m-contig per XCD
    const int m0 = (w >> 3) * 128;
    const int n0 = (w & 7) * 128;

    const f16* W; const float* bias;
    if (z == 0)      { W = Wq16; bias = bq; }
    else if (z == 1) { W = Wk16; bias = bk; }
    else             { W = Wv16; bias = bv; }

    const int t    = threadIdx.x;
    const int lane = t & 63;
    const int wid  = t >> 6;
    const int wm   = (wid >> 1) * 64;
    const int wn   = (wid & 1) * 64;
    const int lr   = lane & 15;
    const int quad = lane >> 4;

    f32x4 acc[4][4];
#pragma unroll
    for (int i = 0; i < 4; i++)
#pragma unroll
        for (int j = 0; j < 4; j++) acc[i][j] = (f32x4){0.f, 0.f, 0.f, 0.f};

    // Staging: 1024 16B-chunks per tile; thread t handles c = t + 256*i.
    // row = c>>3 (8 chunks/row), phys chunk = c&7, logical = phys ^ (row&7).
    const f16* asrc[4]; const f16* bsrc[4];
#pragma unroll
    for (int i = 0; i < 4; i++) {
        const int c   = t + 256 * i;
        const int row = c >> 3;
        const int lc  = ((c & 7) ^ (row & 7)) * 8;
        int am = m0 + row; if (am >= MROWS) am = MROWS - 1;   // clamp tail
        asrc[i] = A + (size_t)am * DM + lc;
        bsrc[i] = W + (size_t)(n0 + row) * DM + lc;
    }

    // Prologue: stage k0 = 0 into buffer 0.
#pragma unroll
    for (int i = 0; i < 4; i++)
        load_lds_16(asrc[i], As[0] + (t + 256 * i) * 8);
#pragma unroll
    for (int i = 0; i < 4; i++)
        load_lds_16(bsrc[i], Bs[0] + (t + 256 * i) * 8);

    int cur = 0;
    for (int k0 = 0; k0 < DM; k0 += 64) {
        __syncthreads();     // buf[cur] DMA drained; prev-step reads done
        if (k0 + 64 < DM) {  // prefetch next step into buf[cur^1]
#pragma unroll
            for (int i = 0; i < 4; i++)
                load_lds_16(asrc[i] + k0 + 64, As[cur ^ 1] + (t + 256 * i) * 8);
#pragma unroll
            for (int i = 0; i < 4; i++)
                load_lds_16(bsrc[i] + k0 + 64, Bs[cur ^ 1] + (t + 256 * i) * 8);
        }

#pragma unroll
        for (int kk = 0; kk < 2; kk++) {
            // Fragment phys chunk (per lane): (kk*4+quad) ^ (lr&7)
            const int fph = ((kk * 4 + quad) ^ (lr & 7)) * 8;
            f16x8 af[4], bf[4];
#pragma unroll
            for (int i = 0; i < 4; i++) {
                af[i] = *(const f16x8*)&As[cur][(wm + i * 16 + lr) * 64 + fph];
                bf[i] = *(const f16x8*)&Bs[cur][(wn + i * 16 + lr) * 64 + fph];
            }
            __builtin_amdgcn_s_setprio(1);
#pragma unroll
            for (int i = 0; i < 4; i++)
#pragma unroll
                for (int j = 0; j < 4; j++)
                    acc[i][j] = MFMA_16x16x32_F16(af[i], bf[j], acc[i][j]);
            __builtin_amdgcn_s_setprio(0);
        }
        cur ^= 1;
    }

    // Epilogue. C/D layout: row = quad*4+reg, col = lane&15 (m89-verified).
#pragma unroll
    for (int j = 0; j < 4; j++) {
        const int n  = n0 + wn + j * 16 + lr;
        const float bv_ = bias[n];
        const int h = n >> 6, d = n & 63;
#pragma unroll
        for (int i = 0; i < 4; i++) {
#pragma unroll
            for (int r = 0; r < 4; r++) {
                const int m = m0 + wm + i * 16 + quad * 4 + r;
                if (m < MROWS) {
                    const int b = m / SQ, s = m % SQ;
                    const f16 val = (f16)(acc[i][j][r] + bv_);
                    if (z == 2) {
                        Vto[((size_t)((b * NHEADS + h) * DH + d)) * SP + s] = val;
                    } else {
                        f16* outp = (z == 0) ? Qo : Ko;
                        outp[(((size_t)(b * NHEADS + h)) * SQ + s) * DH + d] = val;
                    }
                }
            }
        }
    }
}

// ---------------------------------------------------------------------------
// Kernel 2: flash attention, swapped-QK^T, QBLK=256 (R12-verified) —
// now PAIR-STAGED: stage TWO 64-row K/V tiles per barrier into a 4-buffer
// ring, compute both with the verbatim per-tile code. Barrier/vmcnt-drain
// events halve (22 -> 11+prologue); staged bytes, registers (~104 VGPR),
// and per-tile index math identical to R12. LDS 64 KB -> 2 blocks/CU,
// 16 waves/CU (same occupancy band as R12).
// ---------------------------------------------------------------------------
__global__ __launch_bounds__(512) void attn_kernel(
    const f16* __restrict__ Q,   // [B*H, SQ, DH]
    const f16* __restrict__ K,   // [B*H, SQ, DH]
    const f16* __restrict__ Vt,  // [B*H, DH, SP]
    float* __restrict__ out)     // [B, SQ, DM]
{
    __shared__ f16 Kt[4][64 * 64];    // 32 KB (4-buffer ring)
    __shared__ f16 Vs[4][64 * 64];    // 32 KB

    // --- XCD-aware decomposition: 768 blocks = 8 xcd * 16 heads * 6 qt ---
    const int L   = blockIdx.x;
    const int xcd = L & 7;
    const int g   = L >> 3;              // 0..95
    const int bh  = xcd * 16 + g / NQT;  // 6 consecutive g share a head
    const int q0  = (g % NQT) * 256;
    const int b   = bh >> 4;
    const int h   = bh & 15;

    const int t    = threadIdx.x;
    const int lane = t & 63;
    const int wid  = t >> 6;             // 0..7
    const int lr   = lane & 15;
    const int quad = lane >> 4;

    const f16* Qb = Q  + (size_t)bh * SQ * DH;
    const f16* Kb = K  + (size_t)bh * SQ * DH;
    const f16* Vb = Vt + (size_t)bh * DH * SP;

    // Q B-fragments for 2 col-blocks (16 q each), pre-scaled by 0.125*log2(e)
    const f16 qs = (f16)0.1803368801f;
    f16x8 qf[2][2];
#pragma unroll
    for (int cb = 0; cb < 2; cb++) {
        int qrow = q0 + wid * 32 + cb * 16 + lr;
        if (qrow >= SQ) qrow = SQ - 1;
        qf[cb][0] = *(const f16x8*)(Qb + (size_t)qrow * DH + quad * 8) * qs;
        qf[cb][1] = *(const f16x8*)(Qb + (size_t)qrow * DH + 32 + quad * 8) * qs;
    }

    // O^T accumulators: o[cb][db][r] = O^T[d = db*16+quad*4+r][q = ...+cb*16+lr]
    f32x4 o[2][4];
#pragma unroll
    for (int cb = 0; cb < 2; cb++)
#pragma unroll
        for (int d = 0; d < 4; d++) o[cb][d] = (f32x4){0.f, 0.f, 0.f, 0.f};
    float lsum[2] = {0.f, 0.f};   // lane-local partial (this quad's k values)
    float mrun = 0.f;             // wave-uniform running max (pre-shift trick)

    // Staging (512 threads): thread t stages row srow = t>>3 (0..63), phys
    // chunk t&7 — one K-chunk + one V-chunk per tile. Logical = phys^(row&7).
    const int srow = t >> 3;
    const int slc  = ((t & 7) ^ (srow & 7)) * 8;
    const f16* ksrc = Kb + (size_t)srow * DH + slc;
    const f16* vsrc = Vb + (size_t)srow * SP + slc;

    // Fragment-read phys chunks (per lane): logical quad / 4+quad
    const int fp0 = ((quad)     ^ (lr & 7)) * 8;
    const int fp1 = ((quad + 4) ^ (lr & 7)) * 8;

#define STAGE(bufi, j0)                                                        \
    do {                                                                       \
        load_lds_16(ksrc + (size_t)(j0) * DH, &Kt[bufi][0] + t * 8);           \
        load_lds_16(vsrc + (j0), &Vs[bufi][0] + t * 8);                        \
    } while (0)

    // Prologue: stage pair 0 (tiles at 0 and 64) into buffers 0,1.
    STAGE(0, 0);
    STAGE(1, 64);
    int pair = 0;

    for (int jp = 0; jp < NJ / 2; ++jp) {
        __syncthreads();                   // current pair staged (vmcnt drains)
        if (jp + 1 < NJ / 2) {             // prefetch next pair into other half
            STAGE((pair ^ 1) * 2,     (jp + 1) * 128);
            STAGE((pair ^ 1) * 2 + 1, (jp + 1) * 128 + 64);
        }

#pragma unroll
        for (int half = 0; half < 2; ++half) {
            const int buf = pair * 2 + half;
            const int j0  = jp * 128 + half * 64;

            // Swapped QK^T: d4[cb][nb] = S^T tile, row = k = quad*4+r, col = q.
            const float nm = -mrun;
            f32x4 d4[2][4];
#pragma unroll
            for (int nb = 0; nb < 4; nb++) {
                const f16x8 kf0 = *(const f16x8*)&Kt[buf][(nb * 16 + lr) * 64 + fp0];
                const f16x8 kf1 = *(const f16x8*)&Kt[buf][(nb * 16 + lr) * 64 + fp1];
#pragma unroll
                for (int cb = 0; cb < 2; cb++) {
                    f32x4 acc = (f32x4){nm, nm, nm, nm};
                    acc = MFMA_16x16x32_F16(kf0, qf[cb][0], acc);
                    acc = MFMA_16x16x32_F16(kf1, qf[cb][1], acc);
                    d4[cb][nb] = acc;
                }
            }
            if (j0 == (NJ - 1) * 64) {         // mask tail keys (k = quad*4+r)
#pragma unroll
                for (int nb = 0; nb < 4; nb++)
#pragma unroll
                    for (int r = 0; r < 4; r++)
                        if (j0 + nb * 16 + quad * 4 + r >= SQ) {
                            d4[0][nb][r] = -__builtin_inff();
                            d4[1][nb][r] = -__builtin_inff();
                        }
            }

            // Wave-shared tile max of d (d <= 0 means no rescale needed)
            float Md = d4[0][0][0];
#pragma unroll
            for (int cb = 0; cb < 2; cb++)
#pragma unroll
                for (int nb = 0; nb < 4; nb++)
#pragma unroll
                    for (int r = 0; r < 4; r++) Md = fmaxf(Md, d4[cb][nb][r]);
#pragma unroll
            for (int off = 1; off < 64; off <<= 1)
                Md = fmaxf(Md, __shfl_xor(Md, off, 64));

            if (Md > 0.f) {                    // rare after early tiles
                const float al = __builtin_amdgcn_exp2f(-Md);
                mrun += Md;
#pragma unroll
                for (int cb = 0; cb < 2; cb++) {
#pragma unroll
                    for (int d = 0; d < 4; d++)
#pragma unroll
                        for (int r = 0; r < 4; r++) o[cb][d][r] *= al;
                    lsum[cb] *= al;
#pragma unroll
                    for (int nb = 0; nb < 4; nb++)
#pragma unroll
                        for (int r = 0; r < 4; r++) d4[cb][nb][r] -= Md;
                }
            }

            // exp2 + pack: pk[cb][nb] is directly the PV MFMA B-fragment
            f16x4 pk[2][4];
#pragma unroll
            for (int cb = 0; cb < 2; cb++)
#pragma unroll
                for (int nb = 0; nb < 4; nb++) {
                    const float e0 = __builtin_amdgcn_exp2f(d4[cb][nb][0]);
                    const float e1 = __builtin_amdgcn_exp2f(d4[cb][nb][1]);
                    const float e2 = __builtin_amdgcn_exp2f(d4[cb][nb][2]);
                    const float e3 = __builtin_amdgcn_exp2f(d4[cb][nb][3]);
                    lsum[cb] += (e0 + e1) + (e2 + e3);
                    const f16x2 lo = __builtin_bit_cast(f16x2, __builtin_amdgcn_cvt_pkrtz(e0, e1));
                    const f16x2 hi = __builtin_bit_cast(f16x2, __builtin_amdgcn_cvt_pkrtz(e2, e3));
                    pk[cb][nb] = __builtin_shufflevector(lo, hi, 0, 1, 2, 3);
                }

            // PV: O^T += V^T-frag (A) * P^T-frag (B), 16x16x16 MFMAs.
#pragma unroll
            for (int nb = 0; nb < 4; nb++) {
                const int vchunk = (((nb * 2) + (quad >> 1)) ^ (lr & 7)) * 8 + (quad & 1) * 4;
#pragma unroll
                for (int db = 0; db < 4; db++) {
                    const f16x4 vfrag =
                        *(const f16x4*)&Vs[buf][(db * 16 + lr) * 64 + vchunk];
#pragma unroll
                    for (int cb = 0; cb < 2; cb++)
                        o[cb][db] = MFMA_16x16x16_F16(vfrag, pk[cb][nb], o[cb][db]);
                }
            }
        }
        pair ^= 1;
    }
#undef STAGE

    // Epilogue: finish lsum across quads, normalize, float4 stores.
#pragma unroll
    for (int cb = 0; cb < 2; cb++) {
        float s = lsum[cb];
        s += __shfl_xor(s, 16, 64);
        s += __shfl_xor(s, 32, 64);
        const int q = q0 + wid * 32 + cb * 16 + lr;
        if (q < SQ) {
            const float inv = 1.0f / s;
            float* op = out + ((size_t)(b * SQ + q)) * DM + h * DH + quad * 4;
#pragma unroll
            for (int db = 0; db < 4; db++) {
                const float4 v4 = {o[cb][db][0] * inv, o[cb][db][1] * inv,
                                   o[cb][db][2] * inv, o[cb][db][3] * inv};
                *(float4*)(op + db * 16) = v4;
            }
        }
    }
}

// ---------------------------------------------------------------------------
extern "C" void kernel_launch(void* const* d_in, const int* in_sizes, int n_in,
                              void* d_out, int out_size, void* d_ws, size_t ws_size,
                              hipStream_t stream) {
    const float* hs = (const float*)d_in[0];
    const float* Wq = (const float*)d_in[1];
    const float* bq = (const float*)d_in[2];
    const float* Wk = (const float*)d_in[3];
    const float* bk = (const float*)d_in[4];
    const float* Wv = (const float*)d_in[5];
    const float* bv = (const float*)d_in[6];
    float* out = (float*)d_out;

    const size_t qk_elems = (size_t)NBATCH * NHEADS * SQ * DH;
    const size_t vt_elems = (size_t)NBATCH * NHEADS * DH * SP;
    const size_t hs_elems = (size_t)MROWS * DM;
    const size_t w_elems  = (size_t)DM * DM;
    f16* Qw   = (f16*)d_ws;
    f16* Kw   = Qw + qk_elems;
    f16* Vtw  = Kw + qk_elems;
    f16* hs16 = Vtw + vt_elems;
    f16* Wq16 = hs16 + hs_elems;
    f16* Wk16 = Wq16 + w_elems;
    f16* Wv16 = Wk16 + w_elems;

    dim3 gcvt(512, 4);
    cvt_kernel<<<gcvt, 256, 0, stream>>>(hs, Wq, Wk, Wv,
                                         hs16, Wq16, Wk16, Wv16,
                                         (int)(hs_elems / 4), (int)(w_elems / 4),
                                         (int)(w_elems / 4), (int)(w_elems / 4));

    // XCD-aware 1-D grid: 86 m-tiles x 8 n-tiles x 3 z = 2064 blocks (R4)
    qkv_gemm_kernel<<<dim3(MT * 8 * 3), 256, 0, stream>>>(
        hs16, Wq16, Wk16, Wv16, bq, bk, bv, Qw, Kw, Vtw);

    // XCD-aware 1-D grid: 8 xcd * 16 heads * 6 q-tiles = 768 blocks
    attn_kernel<<<dim3(768), 512, 0, stream>>>(Qw, Kw, Vtw, out);
}

// Round 14
// 296.959 us; speedup vs baseline: 1.1970x; 1.1970x over previous
//
#include <hip/hip_runtime.h>
#include <stdint.h>
#include <stddef.h>

// Problem constants (DINOv2 self-attention)
#define SQ     1370              // sequence length
#define SP     1408              // padded V^T row stride (covers 22 j-tiles of 64)
#define NJ     22                // ceil(SQ/64) key tiles
#define NBATCH 8
#define NHEADS 16
#define DH     64                // head dim
#define DM     1024              // model dim
#define MROWS  (NBATCH * SQ)     // 10960 flattened rows
#define MT     86                // m-tiles (128 rows each)
#define NQT    6                 // ceil(SQ/256) q-tiles for attn
#define CTS    136               // padded Ct row stride (f16): 128 + 8

typedef _Float16 f16;
typedef __attribute__((ext_vector_type(8))) _Float16 f16x8;
typedef __attribute__((ext_vector_type(4))) _Float16 f16x4;
typedef __attribute__((ext_vector_type(2))) _Float16 f16x2;
typedef __attribute__((ext_vector_type(4))) float    f32x4;

#define MFMA_16x16x32_F16(a, b, c) __builtin_amdgcn_mfma_f32_16x16x32_f16((a), (b), (c), 0, 0, 0)
#define MFMA_16x16x16_F16(a, b, c) __builtin_amdgcn_mfma_f32_16x16x16f16((a), (b), (c), 0, 0, 0)

// Async global->LDS DMA, 16 B per lane. LDS dest must be wave-uniform base +
// lane*16 (hardware constraint); the global side is an ordinary per-lane addr.
__device__ __forceinline__ void load_lds_16(const f16* g, f16* l) {
    __builtin_amdgcn_global_load_lds(
        (const __attribute__((address_space(1))) void*)g,
        (__attribute__((address_space(3))) void*)l, 16, 0, 0);
}

// ---------------------------------------------------------------------------
// Kernel 0: fp32 -> f16 convert (hs + the three weight matrices).
// ---------------------------------------------------------------------------
__global__ __launch_bounds__(256) void cvt_kernel(
    const float* __restrict__ s0, const float* __restrict__ s1,
    const float* __restrict__ s2, const float* __restrict__ s3,
    f16* __restrict__ d0, f16* __restrict__ d1,
    f16* __restrict__ d2, f16* __restrict__ d3,
    int n0, int n1, int n2, int n3)     // counts in float4 units
{
    const float* s; f16* d; int n;
    switch (blockIdx.y) {
        case 0:  s = s0; d = d0; n = n0; break;
        case 1:  s = s1; d = d1; n = n1; break;
        case 2:  s = s2; d = d2; n = n2; break;
        default: s = s3; d = d3; n = n3; break;
    }
    const int stride = gridDim.x * blockDim.x;
    for (int i = blockIdx.x * blockDim.x + threadIdx.x; i < n; i += stride) {
        const float4 v = ((const float4*)s)[i];
        ((f16x4*)d)[i] = (f16x4){(f16)v.x, (f16)v.y, (f16)v.z, (f16)v.w};
    }
}

// ---------------------------------------------------------------------------
// Kernel 1: QKV projection GEMM — R4 K-loop verbatim (~143 µs anchor);
// NEW: z==2 (V^T) epilogue stages the C-tile in LDS (transposed, padded)
// and writes coalesced 16B chunks. Old path: 2-byte scatters at 2816-B
// stride -> ~27 MB partial-line write overfetch (WRITE 94 vs 67 MB ideal).
// LDS reused after a __syncthreads(); single 64 KB block (As/Bs carved).
// ---------------------------------------------------------------------------
__global__ __launch_bounds__(256) void qkv_gemm_kernel(
    const f16* __restrict__ A,        // [MROWS][DM] f16
    const f16* __restrict__ Wq16, const f16* __restrict__ Wk16,
    const f16* __restrict__ Wv16,
    const float* __restrict__ bq, const float* __restrict__ bk,
    const float* __restrict__ bv,
    f16* __restrict__ Qo, f16* __restrict__ Ko, f16* __restrict__ Vto)
{
    __shared__ f16 SH[32768];         // 64 KB: As[2] | Bs[2]; Ct reuses all
    f16 (*As)[128 * 64] = (f16(*)[128 * 64])(SH);
    f16 (*Bs)[128 * 64] = (f16(*)[128 * 64])(SH + 16384);

    // --- XCD-aware work decomposition ---
    const int L = blockIdx.x;         // 0..2063
    const int x = L & 7;              // XCD (round-robin dispatch assumption)
    const int g = L >> 3;             // per-XCD sequence 0..257
    const int z = g / MT;             // 0..2  (z outer)
    const int w = x * MT + (g % MT);  // within-z work id 0..687, m-contig per XCD
    const int m0 = (w >> 3) * 128;
    const int n0 = (w & 7) * 128;

    const f16* W; const float* bias;
    if (z == 0)      { W = Wq16; bias = bq; }
    else if (z == 1) { W = Wk16; bias = bk; }
    else             { W = Wv16; bias = bv; }

    const int t    = threadIdx.x;
    const int lane = t & 63;
    const int wid  = t >> 6;
    const int wm   = (wid >> 1) * 64;
    const int wn   = (wid & 1) * 64;
    const int lr   = lane & 15;
    const int quad = lane >> 4;

    f32x4 acc[4][4];
#pragma unroll
    for (int i = 0; i < 4; i++)
#pragma unroll
        for (int j = 0; j < 4; j++) acc[i][j] = (f32x4){0.f, 0.f, 0.f, 0.f};

    // Staging: 1024 16B-chunks per tile; thread t handles c = t + 256*i.
    // row = c>>3 (8 chunks/row), phys chunk = c&7, logical = phys ^ (row&7).
    const f16* asrc[4]; const f16* bsrc[4];
#pragma unroll
    for (int i = 0; i < 4; i++) {
        const int c   = t + 256 * i;
        const int row = c >> 3;
        const int lc  = ((c & 7) ^ (row & 7)) * 8;
        int am = m0 + row; if (am >= MROWS) am = MROWS - 1;   // clamp tail
        asrc[i] = A + (size_t)am * DM + lc;
        bsrc[i] = W + (size_t)(n0 + row) * DM + lc;
    }

    // Prologue: stage k0 = 0 into buffer 0.
#pragma unroll
    for (int i = 0; i < 4; i++)
        load_lds_16(asrc[i], As[0] + (t + 256 * i) * 8);
#pragma unroll
    for (int i = 0; i < 4; i++)
        load_lds_16(bsrc[i], Bs[0] + (t + 256 * i) * 8);

    int cur = 0;
    for (int k0 = 0; k0 < DM; k0 += 64) {
        __syncthreads();     // buf[cur] DMA drained; prev-step reads done
        if (k0 + 64 < DM) {  // prefetch next step into buf[cur^1]
#pragma unroll
            for (int i = 0; i < 4; i++)
                load_lds_16(asrc[i] + k0 + 64, As[cur ^ 1] + (t + 256 * i) * 8);
#pragma unroll
            for (int i = 0; i < 4; i++)
                load_lds_16(bsrc[i] + k0 + 64, Bs[cur ^ 1] + (t + 256 * i) * 8);
        }

#pragma unroll
        for (int kk = 0; kk < 2; kk++) {
            // Fragment phys chunk (per lane): (kk*4+quad) ^ (lr&7)
            const int fph = ((kk * 4 + quad) ^ (lr & 7)) * 8;
            f16x8 af[4], bf[4];
#pragma unroll
            for (int i = 0; i < 4; i++) {
                af[i] = *(const f16x8*)&As[cur][(wm + i * 16 + lr) * 64 + fph];
                bf[i] = *(const f16x8*)&Bs[cur][(wn + i * 16 + lr) * 64 + fph];
            }
            __builtin_amdgcn_s_setprio(1);
#pragma unroll
            for (int i = 0; i < 4; i++)
#pragma unroll
                for (int j = 0; j < 4; j++)
                    acc[i][j] = MFMA_16x16x32_F16(af[i], bf[j], acc[i][j]);
            __builtin_amdgcn_s_setprio(0);
        }
        cur ^= 1;
    }

    // Epilogue. C/D layout: row = quad*4+reg, col = lane&15 (m89-verified).
    if (z != 2) {
#pragma unroll
        for (int j = 0; j < 4; j++) {
            const int n  = n0 + wn + j * 16 + lr;
            const float bv_ = bias[n];
            const int h = n >> 6, d = n & 63;
            f16* outp = (z == 0) ? Qo : Ko;
#pragma unroll
            for (int i = 0; i < 4; i++) {
#pragma unroll
                for (int r = 0; r < 4; r++) {
                    const int m = m0 + wm + i * 16 + quad * 4 + r;
                    if (m < MROWS) {
                        const int b = m / SQ, s = m % SQ;
                        outp[(((size_t)(b * NHEADS + h)) * SQ + s) * DH + d] =
                            (f16)(acc[i][j][r] + bv_);
                    }
                }
            }
        }
    } else {
        // V^T: stage C^T in LDS (Ct[nloc][mloc], padded stride CTS), then
        // write coalesced 16B chunks along m (contiguous s in Vto rows).
        __syncthreads();                      // all waves done reading As/Bs
        f16* Ct = SH;                         // 128 * CTS * 2 = 34.8 KB
#pragma unroll
        for (int j = 0; j < 4; j++) {
            const int nloc = wn + j * 16 + lr;
            const float bv_ = bias[n0 + nloc];
#pragma unroll
            for (int i = 0; i < 4; i++)
#pragma unroll
                for (int r = 0; r < 4; r++)
                    Ct[nloc * CTS + wm + i * 16 + quad * 4 + r] =
                        (f16)(acc[i][j][r] + bv_);
        }
        __syncthreads();
        // Write-out: 2048 chunks (128 nloc x 16 m-chunks of 8); thread t
        // handles chunks {t + 256*cc}. 16 consecutive lanes = one nloc row
        // = 256 B contiguous in Vto.
#pragma unroll
        for (int cc = 0; cc < 8; cc++) {
            const int c    = t + 256 * cc;
            const int nloc = c >> 4;
            const int ml   = (c & 15) * 8;
            const int m    = m0 + ml;
            const int h    = (n0 + nloc) >> 6, d = (n0 + nloc) & 63;
            if (m + 7 < MROWS && (m / SQ) == ((m + 7) / SQ)) {
                const int b = m / SQ, s = m % SQ;
                *(f16x8*)(Vto + ((size_t)((b * NHEADS + h) * DH + d)) * SP + s) =
                    *(const f16x8*)&Ct[nloc * CTS + ml];
            } else {                          // batch-boundary / tail chunk
#pragma unroll
                for (int u = 0; u < 8; u++) {
                    const int mu = m + u;
                    if (mu < MROWS) {
                        const int b = mu / SQ, s = mu % SQ;
                        Vto[((size_t)((b * NHEADS + h) * DH + d)) * SP + s] =
                            Ct[nloc * CTS + ml + u];
                    }
                }
            }
        }
    }
}

// ---------------------------------------------------------------------------
// Kernel 2: flash attention, swapped-QK^T, QBLK=256 — R12 VERBATIM (best:
// attn below 142 µs; R13's pair-staging regressed and is reverted).
// ---------------------------------------------------------------------------
__global__ __launch_bounds__(512) void attn_kernel(
    const f16* __restrict__ Q,   // [B*H, SQ, DH]
    const f16* __restrict__ K,   // [B*H, SQ, DH]
    const f16* __restrict__ Vt,  // [B*H, DH, SP]
    float* __restrict__ out)     // [B, SQ, DM]
{
    __shared__ f16 Kt[2][64 * 64];    // 16 KB
    __shared__ f16 Vs[2][64 * 64];    // 16 KB

    // --- XCD-aware decomposition: 768 blocks = 8 xcd * 16 heads * 6 qt ---
    const int L   = blockIdx.x;
    const int xcd = L & 7;
    const int g   = L >> 3;              // 0..95
    const int bh  = xcd * 16 + g / NQT;  // 6 consecutive g share a head
    const int q0  = (g % NQT) * 256;
    const int b   = bh >> 4;
    const int h   = bh & 15;

    const int t    = threadIdx.x;
    const int lane = t & 63;
    const int wid  = t >> 6;             // 0..7
    const int lr   = lane & 15;
    const int quad = lane >> 4;

    const f16* Qb = Q  + (size_t)bh * SQ * DH;
    const f16* Kb = K  + (size_t)bh * SQ * DH;
    const f16* Vb = Vt + (size_t)bh * DH * SP;

    // Q B-fragments for 2 col-blocks (16 q each), pre-scaled by 0.125*log2(e)
    const f16 qs = (f16)0.1803368801f;
    f16x8 qf[2][2];
#pragma unroll
    for (int cb = 0; cb < 2; cb++) {
        int qrow = q0 + wid * 32 + cb * 16 + lr;
        if (qrow >= SQ) qrow = SQ - 1;
        qf[cb][0] = *(const f16x8*)(Qb + (size_t)qrow * DH + quad * 8) * qs;
        qf[cb][1] = *(const f16x8*)(Qb + (size_t)qrow * DH + 32 + quad * 8) * qs;
    }

    // O^T accumulators: o[cb][db][r] = O^T[d = db*16+quad*4+r][q = ...+cb*16+lr]
    f32x4 o[2][4];
#pragma unroll
    for (int cb = 0; cb < 2; cb++)
#pragma unroll
        for (int d = 0; d < 4; d++) o[cb][d] = (f32x4){0.f, 0.f, 0.f, 0.f};
    float lsum[2] = {0.f, 0.f};   // lane-local partial (this quad's k values)
    float mrun = 0.f;             // wave-uniform running max (pre-shift trick)

    // Staging (512 threads): thread t stages row srow = t>>3 (0..63), phys
    // chunk t&7 — one K-chunk + one V-chunk per tile. Logical = phys^(row&7).
    const int srow = t >> 3;
    const int slc  = ((t & 7) ^ (srow & 7)) * 8;
    const f16* ksrc = Kb + (size_t)srow * DH + slc;
    const f16* vsrc = Vb + (size_t)srow * SP + slc;

    // Fragment-read phys chunks (per lane): logical quad / 4+quad
    const int fp0 = ((quad)     ^ (lr & 7)) * 8;
    const int fp1 = ((quad + 4) ^ (lr & 7)) * 8;

#define STAGE(bufi, j0)                                                        \
    do {                                                                       \
        load_lds_16(ksrc + (size_t)(j0) * DH, &Kt[bufi][0] + t * 8);           \
        load_lds_16(vsrc + (j0), &Vs[bufi][0] + t * 8);                        \
    } while (0)

    STAGE(0, 0);
    int buf = 0;

    for (int jt = 0; jt < NJ; ++jt) {
        const int j0 = jt * 64;
        __syncthreads();                       // buf staged (vmcnt drains here)
        if (jt + 1 < NJ) STAGE(buf ^ 1, j0 + 64);

        // Swapped QK^T: d4[cb][nb] = S^T tile, row = k = quad*4+r, col = q = lr.
        const float nm = -mrun;
        f32x4 d4[2][4];
#pragma unroll
        for (int nb = 0; nb < 4; nb++) {
            const f16x8 kf0 = *(const f16x8*)&Kt[buf][(nb * 16 + lr) * 64 + fp0];
            const f16x8 kf1 = *(const f16x8*)&Kt[buf][(nb * 16 + lr) * 64 + fp1];
#pragma unroll
            for (int cb = 0; cb < 2; cb++) {
                f32x4 acc = (f32x4){nm, nm, nm, nm};
                acc = MFMA_16x16x32_F16(kf0, qf[cb][0], acc);
                acc = MFMA_16x16x32_F16(kf1, qf[cb][1], acc);
                d4[cb][nb] = acc;
            }
        }
        if (jt == NJ - 1) {                    // mask tail keys (k = quad*4+r)
#pragma unroll
            for (int nb = 0; nb < 4; nb++)
#pragma unroll
                for (int r = 0; r < 4; r++)
                    if (j0 + nb * 16 + quad * 4 + r >= SQ) {
                        d4[0][nb][r] = -__builtin_inff();
                        d4[1][nb][r] = -__builtin_inff();
                    }
        }

        // Wave-shared tile max of d (d <= 0 means no rescale needed)
        float Md = d4[0][0][0];
#pragma unroll
        for (int cb = 0; cb < 2; cb++)
#pragma unroll
            for (int nb = 0; nb < 4; nb++)
#pragma unroll
                for (int r = 0; r < 4; r++) Md = fmaxf(Md, d4[cb][nb][r]);
#pragma unroll
        for (int off = 1; off < 64; off <<= 1)
            Md = fmaxf(Md, __shfl_xor(Md, off, 64));

        if (Md > 0.f) {                        // rare after early tiles
            const float al = __builtin_amdgcn_exp2f(-Md);
            mrun += Md;
#pragma unroll
            for (int cb = 0; cb < 2; cb++) {
#pragma unroll
                for (int d = 0; d < 4; d++)
#pragma unroll
                    for (int r = 0; r < 4; r++) o[cb][d][r] *= al;
                lsum[cb] *= al;
#pragma unroll
                for (int nb = 0; nb < 4; nb++)
#pragma unroll
                    for (int r = 0; r < 4; r++) d4[cb][nb][r] -= Md;
            }
        }

        // exp2 + pack: pk[cb][nb] is directly the PV MFMA B-fragment
        f16x4 pk[2][4];
#pragma unroll
        for (int cb = 0; cb < 2; cb++)
#pragma unroll
            for (int nb = 0; nb < 4; nb++) {
                const float e0 = __builtin_amdgcn_exp2f(d4[cb][nb][0]);
                const float e1 = __builtin_amdgcn_exp2f(d4[cb][nb][1]);
                const float e2 = __builtin_amdgcn_exp2f(d4[cb][nb][2]);
                const float e3 = __builtin_amdgcn_exp2f(d4[cb][nb][3]);
                lsum[cb] += (e0 + e1) + (e2 + e3);
                const f16x2 lo = __builtin_bit_cast(f16x2, __builtin_amdgcn_cvt_pkrtz(e0, e1));
                const f16x2 hi = __builtin_bit_cast(f16x2, __builtin_amdgcn_cvt_pkrtz(e2, e3));
                pk[cb][nb] = __builtin_shufflevector(lo, hi, 0, 1, 2, 3);
            }

        // PV: O^T += V^T-frag (A) * P^T-frag (B), 16x16x16 MFMAs.
#pragma unroll
        for (int nb = 0; nb < 4; nb++) {
            const int vchunk = (((nb * 2) + (quad >> 1)) ^ (lr & 7)) * 8 + (quad & 1) * 4;
#pragma unroll
            for (int db = 0; db < 4; db++) {
                const f16x4 vfrag =
                    *(const f16x4*)&Vs[buf][(db * 16 + lr) * 64 + vchunk];
#pragma unroll
                for (int cb = 0; cb < 2; cb++)
                    o[cb][db] = MFMA_16x16x16_F16(vfrag, pk[cb][nb], o[cb][db]);
            }
        }
        buf ^= 1;
    }
#undef STAGE

    // Epilogue: finish lsum across quads, normalize, float4 stores.
#pragma unroll
    for (int cb = 0; cb < 2; cb++) {
        float s = lsum[cb];
        s += __shfl_xor(s, 16, 64);
        s += __shfl_xor(s, 32, 64);
        const int q = q0 + wid * 32 + cb * 16 + lr;
        if (q < SQ) {
            const float inv = 1.0f / s;
            float* op = out + ((size_t)(b * SQ + q)) * DM + h * DH + quad * 4;
#pragma unroll
            for (int db = 0; db < 4; db++) {
                const float4 v4 = {o[cb][db][0] * inv, o[cb][db][1] * inv,
                                   o[cb][db][2] * inv, o[cb][db][3] * inv};
                *(float4*)(op + db * 16) = v4;
            }
        }
    }
}

// ---------------------------------------------------------------------------
extern "C" void kernel_launch(void* const* d_in, const int* in_sizes, int n_in,
                              void* d_out, int out_size, void* d_ws, size_t ws_size,
                              hipStream_t stream) {
    const float* hs = (const float*)d_in[0];
    const float* Wq = (const float*)d_in[1];
    const float* bq = (const float*)d_in[2];
    const float* Wk = (const float*)d_in[3];
    const float* bk = (const float*)d_in[4];
    const float* Wv = (const float*)d_in[5];
    const float* bv = (const float*)d_in[6];
    float* out = (float*)d_out;

    const size_t qk_elems = (size_t)NBATCH * NHEADS * SQ * DH;
    const size_t vt_elems = (size_t)NBATCH * NHEADS * DH * SP;
    const size_t hs_elems = (size_t)MROWS * DM;
    const size_t w_elems  = (size_t)DM * DM;
    f16* Qw   = (f16*)d_ws;
    f16* Kw   = Qw + qk_elems;
    f16* Vtw  = Kw + qk_elems;
    f16* hs16 = Vtw + vt_elems;
    f16* Wq16 = hs16 + hs_elems;
    f16* Wk16 = Wq16 + w_elems;
    f16* Wv16 = Wk16 + w_elems;

    dim3 gcvt(512, 4);
    cvt_kernel<<<gcvt, 256, 0, stream>>>(hs, Wq, Wk, Wv,
                                         hs16, Wq16, Wk16, Wv16,
                                         (int)(hs_elems / 4), (int)(w_elems / 4),
                                         (int)(w_elems / 4), (int)(w_elems / 4));

    // XCD-aware 1-D grid: 86 m-tiles x 8 n-tiles x 3 z = 2064 blocks (R4)
    qkv_gemm_kernel<<<dim3(MT * 8 * 3), 256, 0, stream>>>(
        hs16, Wq16, Wk16, Wv16, bq, bk, bv, Qw, Kw, Vtw);

    // XCD-aware 1-D grid: 8 xcd * 16 heads * 6 q-tiles = 768 blocks (R12)
    attn_kernel<<<dim3(768), 512, 0, stream>>>(Qw, Kw, Vtw, out);
}